// Round 6
// baseline (313.622 us; speedup 1.0000x reference)
//
#include <hip/hip_runtime.h>
#include <stdint.h>

// QNetSNN: B=16384, HIDDEN=64, T=40. Wave=row, lane=neuron.
// R6: (a) fold stream served by an L2-resident pair-sum dictionary
//     (2 bits per 8B load, off the LDS pipe), (b) complement trick caps every
//     64-bit stream at 32 bits, (c) global set shrunk to pair-only 32 KB (L1),
//     wsin/wain moved to LDS. Fallback to proven R4 kernel if ws too small.
//
// Fast-path memory map:
//   ws: dict f64 [4096][64] (2 MB)  @ double-idx 0      dict[(k1<<6|k2)<<6|n]
//       pair f32x2 [64][64] (32 KB) @ double-idx 262144 {Warec[n][k], Wcin[n][k]}
//   LDS (48 KB): wsrec f64 [k][n] 32 KB | wsin f32 [48][64] 12 KB | wain f32 [8][64] 2 KB

__device__ __forceinline__ uint64_t rfl64(uint64_t x) {
    uint32_t lo = (uint32_t)__builtin_amdgcn_readfirstlane((int)(uint32_t)(x & 0xFFFFFFFFull));
    uint32_t hi = (uint32_t)__builtin_amdgcn_readfirstlane((int)(uint32_t)(x >> 32));
    return ((uint64_t)hi << 32) | (uint64_t)lo;
}

// ======================= R6 fast path =======================

__global__ void snn_prep6(const float* __restrict__ Warec, const float* __restrict__ Wcin,
                          const float* __restrict__ Wcrec, double* __restrict__ ws) {
    int tid = blockIdx.x * 256 + threadIdx.x;     // 0 .. 278527
    if (tid < 262144) {
        // dict[(k1<<6|k2)<<6|n] = fold(n,k1) + (k1!=k2 ? fold(n,k2) : 0)
        int n  = tid & 63;
        int pr = tid >> 6;
        int k2 = pr & 63;
        int k1 = pr >> 6;
        double f1 = (double)Wcin[n * 128 + 64 + k1] + (double)Wcrec[n * 64 + k1];
        double v  = f1;
        if (k1 != k2) v += (double)Wcin[n * 128 + 64 + k2] + (double)Wcrec[n * 64 + k2];
        ws[tid] = v;
    } else {
        int e = tid - 262144;                      // 0 .. 16383 : pair floats
        if (e < 16384) {
            float* pf = (float*)(ws + 262144);
            int pidx = e >> 1;                     // (k<<6)|n
            int comp = e & 1;
            int k = pidx >> 6, n = pidx & 63;
            pf[e] = comp ? Wcin[n * 128 + k] : Warec[n * 64 + k];
        }
    }
}

__launch_bounds__(1024, 4)
__global__ void snn_main6(const float* __restrict__ state, const float* __restrict__ action,
                          const float* __restrict__ Wsrec, const float* __restrict__ Wsin,
                          const float* __restrict__ Wain, const float* __restrict__ Wro,
                          const double* __restrict__ ws, float* __restrict__ out) {
    __shared__ double wsrecL[4096];   // [k<<6|n] f64, 32 KB
    __shared__ float  wsinL[3072];    // [k*64+n], 12 KB
    __shared__ float  wainL[512];     // [k*64+n], 2 KB

    const int tid = threadIdx.x;
    for (int e = tid; e < 7680; e += 1024) {
        if (e < 4096) {
            int k = e >> 6, n = e & 63;
            wsrecL[e] = (double)Wsrec[n * 64 + k];
        } else if (e < 7168) {
            int r = e - 4096; int k = r >> 6, n = r & 63;
            wsinL[r] = Wsin[n * 48 + k];
        } else {
            int r = e - 7168; int k = r >> 6, n = r & 63;
            wainL[r] = Wain[n * 8 + k];
        }
    }
    __syncthreads();

    const int lane = tid & 63;
    const int wave = tid >> 6;
    const int row  = blockIdx.x * 16 + wave;

    const double* __restrict__ dict  = ws;
    const float2* __restrict__ pair  = (const float2*)(ws + 262144);
    const float wro = Wro[lane];

    double cur = 0.0;
    if (lane < 24)      cur = fmax( 50.0 * (double)state[row * 24 + lane], 0.0);
    else if (lane < 48) cur = fmax(-50.0 * (double)state[row * 24 + lane - 24], 0.0);
    else if (lane < 52) cur = fmax( 50.0 * (double)action[row * 4 + lane - 48], 0.0);
    else if (lane < 56) cur = fmax(-50.0 * (double)action[row * 4 + lane - 52], 0.0);

    // Always-on lanes: venc = 0.1*cur bit-identically each step -> exact predicate.
    double v1 = 0.0 + 0.1 * (cur - 0.0);
    bool alw = (v1 - 1.0) > 0.0;
    double curv = alw ? 0.0 : cur;
    uint64_t AM = rfl64(__ballot(alw));

    // Per-lane column totals (f64) for the complement trick.
    double Tsrec = 0.0, TA = 0.0, TC = 0.0, Tfold = 0.0;
    for (int k = 0; k < 64; ++k) {
        Tsrec += wsrecL[(k << 6) + lane];
        float2 w = pair[(k << 6) + lane];
        TA += (double)w.x; TC += (double)w.y;
        Tfold += dict[(((k << 6) | k) << 6) + lane];   // diagonal = fold(n,k)
    }

    // Always-on input sums.
    double Ssin = 0.0, Sain = 0.0;
    {
        uint64_t m = AM & 0x0000FFFFFFFFFFFFull;
        while (m) { int k = __builtin_ctzll(m); m &= m - 1; Ssin += (double)wsinL[(k << 6) + lane]; }
        m = AM >> 48;
        while (m) { int k = __builtin_ctzll(m); m &= m - 1; Sain += (double)wainL[(k << 6) + lane]; }
    }

    double venc = 0.0, v = 0.0, icur = 0.0, vli = 0.0, ili = 0.0, vmax = 0.0;
    uint64_t zmask = 0;  // z_c of previous step

    for (int t = 0; t < 40; ++t) {
        // ---- layer-s threshold (entering v,i only) ----
        double vd = v + 0.1 * (icur - v);
        bool zs = (vd - 1.0) > 0.0;
        double vs_new = zs ? 0.0 : vd;
        uint64_t zsm = rfl64(__ballot(zs));

        // ---- pair loop (global f32x2, L1-resident), complement-capped ----
        bool cP = __builtin_popcountll(zsm) > 32;
        double pA0 = 0.0, pA1 = 0.0, pC0 = 0.0, pC1 = 0.0;
        {
            uint64_t m = cP ? ~zsm : zsm;
            while (m) {
                int k = __builtin_ctzll(m); m &= m - 1;
                float2 w = pair[(k << 6) + lane];
                pA0 += (double)w.x; pC0 += (double)w.y;
                if (m) {
                    k = __builtin_ctzll(m); m &= m - 1;
                    float2 u = pair[(k << 6) + lane];
                    pA1 += (double)u.x; pC1 += (double)u.y;
                }
            }
        }
        double pA = cP ? (TA - (pA0 + pA1)) : (pA0 + pA1);
        double pC = cP ? (TC - (pC0 + pC1)) : (pC0 + pC1);

        // ---- encoder (variable lanes only) ----
        venc = venc + 0.1 * (curv - venc);
        bool esp = (venc - 1.0) > 0.0;
        venc = esp ? 0.0 : venc;
        uint64_t em = rfl64(__ballot(esp));

        // ---- layer s: zmask -> wsrec (LDS f64), complement-capped ----
        bool cS = __builtin_popcountll(zmask) > 32;
        double r0 = 0.0, r1 = 0.0;
        {
            uint64_t m = cS ? ~zmask : zmask;
            while (m) {
                int k = __builtin_ctzll(m); m &= m - 1; r0 += wsrecL[(k << 6) + lane];
                if (m) { k = __builtin_ctzll(m); m &= m - 1; r1 += wsrecL[(k << 6) + lane]; }
            }
        }
        double rS = cS ? (Tsrec - (r0 + r1)) : (r0 + r1);

        double acc = (icur - 0.2 * icur) + Ssin + rS;
        {
            uint64_t m = em & 0x0000FFFFFFFFFFFFull;    // few variable state bits
            while (m) { int k = __builtin_ctzll(m); m &= m - 1; acc += (double)wsinL[(k << 6) + lane]; }
        }
        double icur_s = acc;

        // ---- layer a ----
        vd = vs_new + 0.1 * (icur_s - vs_new);
        bool za = (vd - 1.0) > 0.0;
        double va_new = za ? 0.0 : vd;
        uint64_t zam = rfl64(__ballot(za));

        acc = (icur_s - 0.2 * icur_s) + Sain + pA;
        {
            uint64_t m = (em >> 48);
            while (m) { int k = __builtin_ctzll(m); m &= m - 1; acc += (double)wainL[(k << 6) + lane]; }
        }
        double icur_a = acc;

        // ---- layer c: zam -> fold via pair-sum dict (L2), 2 bits per load ----
        vd = va_new + 0.1 * (icur_a - va_new);
        bool zc = (vd - 1.0) > 0.0;
        v = zc ? 0.0 : vd;
        zmask = rfl64(__ballot(zc));

        bool cF = __builtin_popcountll(zam) > 32;
        double f0 = 0.0, f1 = 0.0;
        {
            uint64_t m = cF ? ~zam : zam;
            while (m) {
                int k1 = __builtin_ctzll(m); m &= m - 1;
                int k2 = k1;
                if (m) { k2 = __builtin_ctzll(m); m &= m - 1; }
                f0 += dict[(((k1 << 6) | k2) << 6) + lane];
                if (m) {
                    k1 = __builtin_ctzll(m); m &= m - 1;
                    k2 = k1;
                    if (m) { k2 = __builtin_ctzll(m); m &= m - 1; }
                    f1 += dict[(((k1 << 6) | k2) << 6) + lane];
                }
            }
        }
        double fS = cF ? (Tfold - (f0 + f1)) : (f0 + f1);
        icur = (icur_a - 0.2 * icur_a) + pC + fS;

        // ---- LI readout (feed-forward -> f32 reduce safe) ----
        float p = zc ? wro : 0.f;
        #pragma unroll
        for (int off = 32; off >= 1; off >>= 1) p += __shfl_xor(p, off, 64);
        double vnew = vli + 0.1 * (ili - vli);
        ili = (ili - 0.2 * ili) + (double)p;
        vli = vnew;
        vmax = fmax(vmax, vli);
    }

    if (lane == 0) out[row] = (float)vmax;
}

// ======================= R4 fallback (proven, 204 us) =======================

__global__ void snn_prep4(const float* __restrict__ Wsin, const float* __restrict__ Wain,
                          const float* __restrict__ Warec, const float* __restrict__ Wcin,
                          float* __restrict__ ws) {
    int tid = blockIdx.x * 256 + threadIdx.x;
    if (tid < 3072) {
        int k = tid >> 6, n = tid & 63;
        ws[tid] = Wsin[n * 48 + k];
    } else if (tid < 3584) {
        int r = tid - 3072; int k = r >> 6, n = r & 63;
        ws[tid] = Wain[n * 8 + k];
    } else if (tid < 11776) {
        int r = tid - 3584; int k = r >> 7; int rem = r & 127; int n = rem >> 1;
        ws[tid] = (rem & 1) ? Wcin[n * 128 + k] : Warec[n * 64 + k];
    }
}

__launch_bounds__(1024, 4)
__global__ void snn_main4(const float* __restrict__ state, const float* __restrict__ action,
                          const float* __restrict__ Wsrec, const float* __restrict__ Wcin,
                          const float* __restrict__ Wcrec, const float* __restrict__ Wro,
                          const float* __restrict__ ws, float* __restrict__ out) {
    __shared__ double lds[8192];
    const int tid = threadIdx.x;
    for (int e = tid; e < 8192; e += 1024) {
        int half = e >> 12; int sub = e & 4095; int k = sub >> 6; int n = sub & 63;
        double val;
        if (half == 0) val = (double)Wsrec[n * 64 + k];
        else           val = (double)Wcin[n * 128 + 64 + k] + (double)Wcrec[n * 64 + k];
        lds[e] = val;
    }
    __syncthreads();
    const int lane = tid & 63; const int wave = tid >> 6; const int row = blockIdx.x * 16 + wave;
    double cur = 0.0;
    if (lane < 24)      cur = fmax( 50.0 * (double)state[row * 24 + lane], 0.0);
    else if (lane < 48) cur = fmax(-50.0 * (double)state[row * 24 + lane - 24], 0.0);
    else if (lane < 52) cur = fmax( 50.0 * (double)action[row * 4 + lane - 48], 0.0);
    else if (lane < 56) cur = fmax(-50.0 * (double)action[row * 4 + lane - 52], 0.0);
    double v1 = 0.0 + 0.1 * (cur - 0.0);
    bool alw = (v1 - 1.0) > 0.0;
    double curv = alw ? 0.0 : cur;
    uint64_t AM = rfl64(__ballot(alw));
    const float*  __restrict__ wsin32 = ws;
    const float*  __restrict__ wain32 = ws + 3072;
    const float2* __restrict__ pair   = (const float2*)(ws + 3584);
    const float wro = Wro[lane];
    double Ssin = 0.0, Sain = 0.0;
    {
        uint64_t m = AM & 0x0000FFFFFFFFFFFFull;
        while (m) { int k = __builtin_ctzll(m); m &= m - 1; Ssin += (double)wsin32[(k << 6) + lane]; }
        m = AM >> 48;
        while (m) { int k = __builtin_ctzll(m); m &= m - 1; Sain += (double)wain32[(k << 6) + lane]; }
    }
    double venc = 0.0, v = 0.0, icur = 0.0, vli = 0.0, ili = 0.0, vmax = 0.0;
    uint64_t zmask = 0;
    for (int t = 0; t < 40; ++t) {
        double vd = v + 0.1 * (icur - v);
        bool zs = (vd - 1.0) > 0.0;
        double vs_new = zs ? 0.0 : vd;
        uint64_t zsm = rfl64(__ballot(zs));
        double pA0 = 0.0, pA1 = 0.0, pC0 = 0.0, pC1 = 0.0;
        {
            uint64_t m = zsm;
            while (m) {
                int k = __builtin_ctzll(m); m &= m - 1;
                float2 w = pair[(k << 6) + lane];
                pA0 += (double)w.x; pC0 += (double)w.y;
                if (m) {
                    k = __builtin_ctzll(m); m &= m - 1;
                    float2 u = pair[(k << 6) + lane];
                    pA1 += (double)u.x; pC1 += (double)u.y;
                }
            }
        }
        venc = venc + 0.1 * (curv - venc);
        bool esp = (venc - 1.0) > 0.0;
        venc = esp ? 0.0 : venc;
        uint64_t em = rfl64(__ballot(esp));
        double acc = (icur - 0.2 * icur) + Ssin;
        {
            uint64_t m = em & 0x0000FFFFFFFFFFFFull;
            while (m) { int k = __builtin_ctzll(m); m &= m - 1; acc += (double)wsin32[(k << 6) + lane]; }
            double a0 = 0.0, a1 = 0.0;
            m = zmask;
            while (m) {
                int k = __builtin_ctzll(m); m &= m - 1; a0 += lds[(k << 6) + lane];
                if (m) { k = __builtin_ctzll(m); m &= m - 1; a1 += lds[(k << 6) + lane]; }
            }
            acc += a0 + a1;
        }
        double icur_s = acc;
        vd = vs_new + 0.1 * (icur_s - vs_new);
        bool za = (vd - 1.0) > 0.0;
        double va_new = za ? 0.0 : vd;
        uint64_t zam = rfl64(__ballot(za));
        acc = (icur_s - 0.2 * icur_s) + Sain + (pA0 + pA1);
        {
            uint64_t m = (em >> 48);
            while (m) { int k = __builtin_ctzll(m); m &= m - 1; acc += (double)wain32[(k << 6) + lane]; }
        }
        double icur_a = acc;
        vd = va_new + 0.1 * (icur_a - va_new);
        bool zc = (vd - 1.0) > 0.0;
        v = zc ? 0.0 : vd;
        zmask = rfl64(__ballot(zc));
        double f0 = 0.0, f1 = 0.0;
        {
            uint64_t m = zam;
            while (m) {
                int k = __builtin_ctzll(m); m &= m - 1;
                f0 += lds[4096 + (k << 6) + lane];
                if (m) { k = __builtin_ctzll(m); m &= m - 1; f1 += lds[4096 + (k << 6) + lane]; }
            }
        }
        icur = (icur_a - 0.2 * icur_a) + (pC0 + pC1) + (f0 + f1);
        float p = zc ? wro : 0.f;
        #pragma unroll
        for (int off = 32; off >= 1; off >>= 1) p += __shfl_xor(p, off, 64);
        double vnew = vli + 0.1 * (ili - vli);
        ili = (ili - 0.2 * ili) + (double)p;
        vli = vnew;
        vmax = fmax(vmax, vli);
    }
    if (lane == 0) out[row] = (float)vmax;
}

extern "C" void kernel_launch(void* const* d_in, const int* in_sizes, int n_in,
                              void* d_out, int out_size, void* d_ws, size_t ws_size,
                              hipStream_t stream) {
    const float* state  = (const float*)d_in[0];
    const float* action = (const float*)d_in[1];
    const float* Wsin   = (const float*)d_in[2];
    const float* Wsrec  = (const float*)d_in[3];
    const float* Wain   = (const float*)d_in[4];
    const float* Warec  = (const float*)d_in[5];
    const float* Wcin   = (const float*)d_in[6];
    const float* Wcrec  = (const float*)d_in[7];
    const float* Wro    = (const float*)d_in[8];
    float* out = (float*)d_out;
    const int B = in_sizes[0] / 24;  // 16384

    const size_t need6 = 262144ull * 8 + 16384ull * 4;   // dict 2MB + pair 64KB
    if (ws_size >= need6) {
        double* ws = (double*)d_ws;
        snn_prep6<<<1088, 256, 0, stream>>>(Warec, Wcin, Wcrec, ws);
        snn_main6<<<B / 16, 1024, 0, stream>>>(state, action, Wsrec, Wsin, Wain, Wro, ws, out);
    } else {
        float* ws = (float*)d_ws;
        snn_prep4<<<46, 256, 0, stream>>>(Wsin, Wain, Warec, Wcin, ws);
        snn_main4<<<B / 16, 1024, 0, stream>>>(state, action, Wsrec, Wcin, Wcrec, Wro, ws, out);
    }
}

// Round 7
// 272.377 us; speedup vs baseline: 1.1514x; 1.1514x over previous
//
#include <hip/hip_runtime.h>
#include <stdint.h>

// QNetSNN: B=16384, HIDDEN=64, T=40. Wave=row, lane=neuron.
// R7 = R4 (proven 204.5us) + 4-wide accumulator unroll in the three hot
// selection loops (more MLP, 1/4 branch overhead) + non-temporal em-stream
// loads so the 32KB pair set owns L1.
//
// LDS 64 KB (f64): wsrec64 [k][n] | fold64 = Wcin[:,64:]+Wcrec [k][n]
// ws   (f32): wsin32_t [48][64] | wain32_t [8][64] | pair float2 [64][64]
//             pair[k*64+n] = { Warec[n][k], Wcin[n][k] }

__device__ __forceinline__ uint64_t rfl64(uint64_t x) {
    uint32_t lo = (uint32_t)__builtin_amdgcn_readfirstlane((int)(uint32_t)(x & 0xFFFFFFFFull));
    uint32_t hi = (uint32_t)__builtin_amdgcn_readfirstlane((int)(uint32_t)(x >> 32));
    return ((uint64_t)hi << 32) | (uint64_t)lo;
}

__global__ void snn_prep(const float* __restrict__ Wsin, const float* __restrict__ Wain,
                         const float* __restrict__ Warec, const float* __restrict__ Wcin,
                         float* __restrict__ ws) {
    int tid = blockIdx.x * 256 + threadIdx.x;   // 0..11775
    if (tid < 3072) {
        int k = tid >> 6, n = tid & 63;
        ws[tid] = Wsin[n * 48 + k];
    } else if (tid < 3584) {
        int r = tid - 3072; int k = r >> 6, n = r & 63;
        ws[tid] = Wain[n * 8 + k];
    } else if (tid < 11776) {
        int r = tid - 3584; int k = r >> 7; int rem = r & 127; int n = rem >> 1;
        ws[tid] = (rem & 1) ? Wcin[n * 128 + k]    // .y = Wcin1 (cols :64)
                            : Warec[n * 64 + k];   // .x = Warec
    }
}

__launch_bounds__(1024, 4)
__global__ void snn_main(const float* __restrict__ state, const float* __restrict__ action,
                         const float* __restrict__ Wsrec, const float* __restrict__ Wcin,
                         const float* __restrict__ Wcrec, const float* __restrict__ Wro,
                         const float* __restrict__ ws, float* __restrict__ out) {
    __shared__ double lds[8192];  // [0,4096) wsrec64 [k][n]; [4096,8192) fold64 [k][n]

    const int tid = threadIdx.x;
    for (int e = tid; e < 8192; e += 1024) {
        int half = e >> 12; int sub = e & 4095; int k = sub >> 6; int n = sub & 63;
        double val;
        if (half == 0) val = (double)Wsrec[n * 64 + k];
        else           val = (double)Wcin[n * 128 + 64 + k] + (double)Wcrec[n * 64 + k];
        lds[e] = val;
    }
    __syncthreads();

    const int lane = tid & 63;
    const int wave = tid >> 6;
    const int row  = blockIdx.x * 16 + wave;

    double cur = 0.0;
    if (lane < 24)      cur = fmax( 50.0 * (double)state[row * 24 + lane], 0.0);
    else if (lane < 48) cur = fmax(-50.0 * (double)state[row * 24 + lane - 24], 0.0);
    else if (lane < 52) cur = fmax( 50.0 * (double)action[row * 4 + lane - 48], 0.0);
    else if (lane < 56) cur = fmax(-50.0 * (double)action[row * 4 + lane - 52], 0.0);

    // Always-on lanes: venc = 0.1*cur bit-identically each step -> exact predicate.
    double v1 = 0.0 + 0.1 * (cur - 0.0);
    bool alw = (v1 - 1.0) > 0.0;
    double curv = alw ? 0.0 : cur;
    uint64_t AM = rfl64(__ballot(alw));

    const float*  __restrict__ wsin32 = ws;
    const float*  __restrict__ wain32 = ws + 3072;
    const float2* __restrict__ pair   = (const float2*)(ws + 3584);
    const float wro = Wro[lane];

    double Ssin = 0.0, Sain = 0.0;
    {
        uint64_t m = AM & 0x0000FFFFFFFFFFFFull;
        while (m) { int k = __builtin_ctzll(m); m &= m - 1; Ssin += (double)__builtin_nontemporal_load(&wsin32[(k << 6) + lane]); }
        m = AM >> 48;
        while (m) { int k = __builtin_ctzll(m); m &= m - 1; Sain += (double)__builtin_nontemporal_load(&wain32[(k << 6) + lane]); }
    }

    double venc = 0.0, v = 0.0, icur = 0.0, vli = 0.0, ili = 0.0, vmax = 0.0;
    uint64_t zmask = 0;  // z_c of previous step

    for (int t = 0; t < 40; ++t) {
        // ---- layer-s threshold (entering v,i only) ----
        double vd = v + 0.1 * (icur - v);
        bool zs = (vd - 1.0) > 0.0;
        double vs_new = zs ? 0.0 : vd;
        uint64_t zsm = rfl64(__ballot(zs));

        // ---- pair loop (global f32x2, L1-resident): Warec + Wcin1, 4-wide ----
        double pA0 = 0.0, pA1 = 0.0, pA2 = 0.0, pA3 = 0.0;
        double pC0 = 0.0, pC1 = 0.0, pC2 = 0.0, pC3 = 0.0;
        {
            uint64_t m = zsm;
            while (m) {
                int k0 = __builtin_ctzll(m); m &= m - 1;
                float2 w0 = pair[(k0 << 6) + lane];
                pA0 += (double)w0.x; pC0 += (double)w0.y;
                if (!m) break;
                int k1 = __builtin_ctzll(m); m &= m - 1;
                float2 w1 = pair[(k1 << 6) + lane];
                pA1 += (double)w1.x; pC1 += (double)w1.y;
                if (!m) break;
                int k2 = __builtin_ctzll(m); m &= m - 1;
                float2 w2 = pair[(k2 << 6) + lane];
                pA2 += (double)w2.x; pC2 += (double)w2.y;
                if (!m) break;
                int k3 = __builtin_ctzll(m); m &= m - 1;
                float2 w3 = pair[(k3 << 6) + lane];
                pA3 += (double)w3.x; pC3 += (double)w3.y;
            }
        }
        double pA = (pA0 + pA1) + (pA2 + pA3);
        double pC = (pC0 + pC1) + (pC2 + pC3);

        // ---- encoder (variable lanes only) ----
        venc = venc + 0.1 * (curv - venc);
        bool esp = (venc - 1.0) > 0.0;
        venc = esp ? 0.0 : venc;
        uint64_t em = rfl64(__ballot(esp));

        // ---- layer s accumulation: zmask -> wsrec (LDS f64), 4-wide ----
        double acc = (icur - 0.2 * icur) + Ssin;
        {
            uint64_t m = em & 0x0000FFFFFFFFFFFFull;   // few variable state bits
            while (m) { int k = __builtin_ctzll(m); m &= m - 1; acc += (double)__builtin_nontemporal_load(&wsin32[(k << 6) + lane]); }
            double a0 = 0.0, a1 = 0.0, a2 = 0.0, a3 = 0.0;
            m = zmask;
            while (m) {
                int k0 = __builtin_ctzll(m); m &= m - 1;
                a0 += lds[(k0 << 6) + lane];
                if (!m) break;
                int k1 = __builtin_ctzll(m); m &= m - 1;
                a1 += lds[(k1 << 6) + lane];
                if (!m) break;
                int k2 = __builtin_ctzll(m); m &= m - 1;
                a2 += lds[(k2 << 6) + lane];
                if (!m) break;
                int k3 = __builtin_ctzll(m); m &= m - 1;
                a3 += lds[(k3 << 6) + lane];
            }
            acc += (a0 + a1) + (a2 + a3);
        }
        double icur_s = acc;

        // ---- layer a ----
        vd = vs_new + 0.1 * (icur_s - vs_new);
        bool za = (vd - 1.0) > 0.0;
        double va_new = za ? 0.0 : vd;
        uint64_t zam = rfl64(__ballot(za));

        acc = (icur_s - 0.2 * icur_s) + Sain + pA;
        {
            uint64_t m = (em >> 48);
            while (m) { int k = __builtin_ctzll(m); m &= m - 1; acc += (double)__builtin_nontemporal_load(&wain32[(k << 6) + lane]); }
        }
        double icur_a = acc;

        // ---- layer c: zam -> fold64 (LDS f64), 4-wide ----
        vd = va_new + 0.1 * (icur_a - va_new);
        bool zc = (vd - 1.0) > 0.0;
        v = zc ? 0.0 : vd;
        zmask = rfl64(__ballot(zc));

        double f0 = 0.0, f1 = 0.0, f2 = 0.0, f3 = 0.0;
        {
            uint64_t m = zam;
            while (m) {
                int k0 = __builtin_ctzll(m); m &= m - 1;
                f0 += lds[4096 + (k0 << 6) + lane];
                if (!m) break;
                int k1 = __builtin_ctzll(m); m &= m - 1;
                f1 += lds[4096 + (k1 << 6) + lane];
                if (!m) break;
                int k2 = __builtin_ctzll(m); m &= m - 1;
                f2 += lds[4096 + (k2 << 6) + lane];
                if (!m) break;
                int k3 = __builtin_ctzll(m); m &= m - 1;
                f3 += lds[4096 + (k3 << 6) + lane];
            }
        }
        icur = (icur_a - 0.2 * icur_a) + pC + ((f0 + f1) + (f2 + f3));

        // ---- LI readout (feed-forward -> f32 reduce safe) ----
        float p = zc ? wro : 0.f;
        #pragma unroll
        for (int off = 32; off >= 1; off >>= 1) p += __shfl_xor(p, off, 64);
        double vnew = vli + 0.1 * (ili - vli);
        ili = (ili - 0.2 * ili) + (double)p;
        vli = vnew;
        vmax = fmax(vmax, vli);
    }

    if (lane == 0) out[row] = (float)vmax;
}

extern "C" void kernel_launch(void* const* d_in, const int* in_sizes, int n_in,
                              void* d_out, int out_size, void* d_ws, size_t ws_size,
                              hipStream_t stream) {
    const float* state  = (const float*)d_in[0];
    const float* action = (const float*)d_in[1];
    const float* Wsin   = (const float*)d_in[2];
    const float* Wsrec  = (const float*)d_in[3];
    const float* Wain   = (const float*)d_in[4];
    const float* Warec  = (const float*)d_in[5];
    const float* Wcin   = (const float*)d_in[6];
    const float* Wcrec  = (const float*)d_in[7];
    const float* Wro    = (const float*)d_in[8];
    float* out = (float*)d_out;
    float* ws  = (float*)d_ws;

    const int B = in_sizes[0] / 24;  // 16384
    snn_prep<<<46, 256, 0, stream>>>(Wsin, Wain, Warec, Wcin, ws);
    snn_main<<<B / 16, 1024, 0, stream>>>(state, action, Wsrec, Wcin, Wcrec, Wro, ws, out);
}